// Round 7
// baseline (547.962 us; speedup 1.0000x reference)
//
#include <hip/hip_runtime.h>
#include <hip/hip_bf16.h>

// GATPooling fused kernel for MI355X (gfx950).
//
// pooled[b] = (sum_i x_i*e_i)/(sum_i e_i), e_i = exp(score_i); scores O(1) -> no
// segment-max pass -> single pass over x (819 MB) -> ~131 us HBM roofline.
//
// R7: R6 + __launch_bounds__(256,4) to pin VGPR <= 128 (4 waves/SIMD = 16 waves/CU).
// R6 likely crossed the 128-VGPR occupancy cliff (2 waves/SIMD), starving the
// latency-hiding TLP this no-prefetch structure relies on. Conversion is interleaved
// with the loads (af[ks] built as soon as its two float4s land) to keep peak live
// registers ~100 so the 128 cap doesn't spill (R5's failure mode).
//
// ws layout: num[nseg*128] f32 | denom[nseg] f32 | w1bf[128*128] bf16 (pre-swizzled)

#define H 128
#define NBLK 1024
#define WPB 4                      // waves per 256-thread block
#define NW (NBLK * WPB)

typedef __attribute__((ext_vector_type(8))) __bf16 bf16x8;
typedef __attribute__((ext_vector_type(4))) float f32x4;

__global__ void gat_init(const float* __restrict__ W1, float* __restrict__ num,
                         float* __restrict__ denom, unsigned short* __restrict__ w1bf,
                         int nseg) {
    int i = blockIdx.x * 256 + threadIdx.x;
    if (i < nseg * H) num[i] = 0.0f;
    if (i < nseg) denom[i] = 0.0f;
    if (i < H * H) {
        int j = i >> 7;               // row of W1 (output feature)
        float f = W1[i];
        unsigned int u = __float_as_uint(f);
        unsigned short b = (unsigned short)((u + 0x7fffu + ((u >> 16) & 1u)) >> 16); // RNE
        int dst = i ^ ((j & 7) << 3); // pre-swizzle at 16B-chunk granularity
        w1bf[dst] = b;
    }
}

__global__ __launch_bounds__(256, 4) void gat_main(
    const float* __restrict__ x, const int* __restrict__ bi,
    const unsigned short* __restrict__ w1bf, const float* __restrict__ b1,
    const float* __restrict__ w2, const float* __restrict__ b2p,
    float* __restrict__ num, float* __restrict__ denom, int E) {

    __shared__ uint4 ldsW[2048];     // 32 KB: W1 bf16, pre-swizzled chunks

    const int t = threadIdx.x;
    const int lane = t & 63;
    const int lr = lane & 15;
    const int lg = lane >> 4;

    const uint4* w1v = (const uint4*)w1bf;
#pragma unroll
    for (int k = 0; k < 8; ++k) ldsW[k * 256 + t] = w1v[k * 256 + t];

    float b1v[8], w2v[8];
#pragma unroll
    for (int nf = 0; nf < 8; ++nf) { b1v[nf] = b1[nf * 16 + lr]; w2v[nf] = w2[nf * 16 + lr]; }
    const float b2v = b2p[0];

    __syncthreads();                 // only barrier in the kernel

    const int gw = blockIdx.x * WPB + (t >> 6);      // global wave id
    const long rbeg = ((long)gw * E) / NW;
    const long rend = ((long)(gw + 1) * E) / NW;     // contiguous slab [rbeg, rend)
    if (rbeg >= rend) return;
    const int nch = (int)((rend - rbeg + 15) >> 4);

    const float4* x4 = (const float4*)x;

    float v[32];                     // pooling acc: col = (i>>3)*32 + lg*8 + (i&7)
#pragma unroll
    for (int i = 0; i < 32; ++i) v[i] = 0.0f;
    float dsum = 0.0f;

    auto flush = [&](int seg) {
        // value-splitting butterfly over the 16 lr-lanes (verified R3-R6)
        {
            const bool h0 = lr & 1;
#pragma unroll
            for (int j = 0; j < 16; ++j) {
                float send = h0 ? v[j] : v[j + 16];
                float recv = __shfl_xor(send, 1, 64);
                v[j] = (h0 ? v[j + 16] : v[j]) + recv;
            }
            const bool h1 = lr & 2;
#pragma unroll
            for (int j = 0; j < 8; ++j) {
                float send = h1 ? v[j] : v[j + 8];
                float recv = __shfl_xor(send, 2, 64);
                v[j] = (h1 ? v[j + 8] : v[j]) + recv;
            }
            const bool h2 = lr & 4;
#pragma unroll
            for (int j = 0; j < 4; ++j) {
                float send = h2 ? v[j] : v[j + 4];
                float recv = __shfl_xor(send, 4, 64);
                v[j] = (h2 ? v[j + 4] : v[j]) + recv;
            }
            const bool h3 = lr & 8;
#pragma unroll
            for (int j = 0; j < 2; ++j) {
                float send = h3 ? v[j] : v[j + 2];
                float recv = __shfl_xor(send, 8, 64);
                v[j] = (h3 ? v[j + 2] : v[j]) + recv;
            }
        }
        int i0 = ((lr & 1) << 4) | ((lr & 2) << 2) | (lr & 4) | ((lr & 8) >> 2);
        int col0 = (i0 >> 3) * 32 + lg * 8 + (i0 & 7);
        atomicAdd(&num[seg * H + col0], v[0]);
        atomicAdd(&num[seg * H + col0 + 1], v[1]);
        float d = dsum;
#pragma unroll
        for (int m = 1; m <= 32; m <<= 1) d += __shfl_xor(d, m, 64);
        if (lane == 0) atomicAdd(&denom[seg], d * 0.25f);   // rows duplicated over 4 lg
#pragma unroll
        for (int i = 0; i < 32; ++i) v[i] = 0.0f;
        dsum = 0.0f;
    };

    int cur = bi[rbeg];

    for (int c = 0; c < nch; ++c) {
        const long r = rbeg + (long)c * 16 + lr;
        const long rc = r < rend ? r : rend - 1;     // clamp inside own slab
        const bool valid = r < rend;

        // ---- load 16 rows x 128 cols; convert each pair to bf16 as it lands ----
        const float4* p = x4 + rc * 32 + lg * 2;
        bf16x8 af[4];
#pragma unroll
        for (int ks = 0; ks < 4; ++ks) {
            const float4 u0 = p[ks * 8];
            const float4 u1 = p[ks * 8 + 1];
            bf16x8 a;
            a[0] = (__bf16)u0.x; a[1] = (__bf16)u0.y; a[2] = (__bf16)u0.z; a[3] = (__bf16)u0.w;
            a[4] = (__bf16)u1.x; a[5] = (__bf16)u1.y; a[6] = (__bf16)u1.z; a[7] = (__bf16)u1.w;
            af[ks] = a;
        }
        const int myseg = bi[rc];

        // ---- MFMA, nf-outer: one live f32x4 accumulator, folded per nf ----
        float sc[4] = {0.f, 0.f, 0.f, 0.f};
#pragma unroll
        for (int nf = 0; nf < 8; ++nf) {
            f32x4 acc = (f32x4)0.0f;
#pragma unroll
            for (int ks = 0; ks < 4; ++ks) {
                int j = nf * 16 + lr;
                int chunk = (j * 16 + ks * 4 + lg) ^ (j & 7);   // XOR swizzle (bank-free)
                bf16x8 bb = __builtin_bit_cast(bf16x8, ldsW[chunk]);
                acc = __builtin_amdgcn_mfma_f32_16x16x32_bf16(af[ks], bb, acc, 0, 0, 0);
            }
            const float bv = b1v[nf], wv = w2v[nf];
#pragma unroll
            for (int r4 = 0; r4 < 4; ++r4)
                sc[r4] = fmaf(fmaxf(acc[r4] + bv, 0.0f), wv, sc[r4]);
        }
        // reduce over the 16 lr-lanes sharing each row (lr = lane bits 0..3)
#pragma unroll
        for (int m = 1; m <= 8; m <<= 1)
#pragma unroll
            for (int r4 = 0; r4 < 4; ++r4) sc[r4] += __shfl_xor(sc[r4], m, 64);

        // e for this lane's row lr: held at lane (lg'=lr>>2, lr'=lr), entry lr&3
        const int src = ((lr >> 2) << 4) | lr;
        float s4[4];
#pragma unroll
        for (int r4 = 0; r4 < 4; ++r4) s4[r4] = __shfl(sc[r4], src, 64);
        const int rsel = lr & 3;
        const float s = rsel == 0 ? s4[0] : rsel == 1 ? s4[1] : rsel == 2 ? s4[2] : s4[3];
        const float e = valid ? __expf(s + b2v) : 0.0f;

        // ---- accumulate into persistent v[], handling (rare) segment changes ----
        while (true) {
            const bool mine = valid && (myseg == cur);
            const float em = mine ? e : 0.0f;
#pragma unroll
            for (int ks = 0; ks < 4; ++ks)
#pragma unroll
                for (int el = 0; el < 8; ++el)
                    v[ks * 8 + el] = fmaf(em, (float)af[ks][el], v[ks * 8 + el]);
            dsum += em;
            unsigned long long rest = __ballot(valid && myseg > cur);
            if (!rest) break;
            flush(cur);
            int idx = __ffsll(rest) - 1;
            cur = __shfl(myseg, idx, 64);
        }
    }
    flush(cur);
}

__global__ void gat_fin(const float* __restrict__ num, const float* __restrict__ denom,
                        float* __restrict__ out, int n) {
    int i = blockIdx.x * 256 + threadIdx.x;
    if (i < n) {
        float d = denom[i >> 7];
        out[i] = (d > 0.0f) ? num[i] / d : 0.0f;
    }
}

extern "C" void kernel_launch(void* const* d_in, const int* in_sizes, int n_in,
                              void* d_out, int out_size, void* d_ws, size_t ws_size,
                              hipStream_t stream) {
    const float* x  = (const float*)d_in[0];
    const int*   bi = (const int*)d_in[1];
    const float* W1 = (const float*)d_in[2];
    const float* b1 = (const float*)d_in[3];
    const float* w2 = (const float*)d_in[4];
    const float* b2 = (const float*)d_in[5];
    const int E = in_sizes[1];
    const int nseg = out_size / H;

    float* num = (float*)d_ws;                               // nseg*H f32
    float* denom = num + (size_t)nseg * H;                   // nseg f32
    unsigned short* w1bf = (unsigned short*)(denom + nseg);  // H*H bf16 (16B-aligned)

    int initN = nseg * H > H * H ? nseg * H : H * H;
    gat_init<<<(initN + 255) / 256, 256, 0, stream>>>(W1, num, denom, w1bf, nseg);
    gat_main<<<NBLK, 256, 0, stream>>>(x, bi, w1bf, b1, w2, b2, num, denom, E);
    gat_fin<<<(out_size + 255) / 256, 256, 0, stream>>>(num, denom, (float*)d_out, out_size);
}

// Round 8
// 189.311 us; speedup vs baseline: 2.8945x; 2.8945x over previous
//
#include <hip/hip_runtime.h>
#include <hip/hip_bf16.h>

// GATPooling fused kernel for MI355X (gfx950).
//
// pooled[b] = (sum_i x_i*e_i)/(sum_i e_i), e_i = exp(score_i); scores O(1) -> no
// segment-max pass -> single pass over x (819 MB) -> ~131 us HBM roofline.
//
// R8: (a) __launch_bounds__(256,2): VGPR cap 256 so the allocator CANNOT squeeze
// below the ~115-reg live set and spill v[32] (R5/R7: VGPR=84/64 -> ~1 GB scratch
// traffic, FETCH 1.8-2.1 GB). (b) dual-chunk iterations (32 rows): one ds_read_b128
// of W1 feeds two MFMAs (halves LDS traffic), serial score/ballot tail amortized 2x,
// 16 KB of loads in flight per wave per iteration.
//
// ws layout: num[nseg*128] f32 | denom[nseg] f32 | w1bf[128*128] bf16 (pre-swizzled)

#define H 128
#define NBLK 1024
#define WPB 4                      // waves per 256-thread block
#define NW (NBLK * WPB)

typedef __attribute__((ext_vector_type(8))) __bf16 bf16x8;
typedef __attribute__((ext_vector_type(4))) float f32x4;

__global__ void gat_init(const float* __restrict__ W1, float* __restrict__ num,
                         float* __restrict__ denom, unsigned short* __restrict__ w1bf,
                         int nseg) {
    int i = blockIdx.x * 256 + threadIdx.x;
    if (i < nseg * H) num[i] = 0.0f;
    if (i < nseg) denom[i] = 0.0f;
    if (i < H * H) {
        int j = i >> 7;               // row of W1 (output feature)
        float f = W1[i];
        unsigned int u = __float_as_uint(f);
        unsigned short b = (unsigned short)((u + 0x7fffu + ((u >> 16) & 1u)) >> 16); // RNE
        int dst = i ^ ((j & 7) << 3); // pre-swizzle at 16B-chunk granularity
        w1bf[dst] = b;
    }
}

__global__ __launch_bounds__(256, 2) void gat_main(
    const float* __restrict__ x, const int* __restrict__ bi,
    const unsigned short* __restrict__ w1bf, const float* __restrict__ b1,
    const float* __restrict__ w2, const float* __restrict__ b2p,
    float* __restrict__ num, float* __restrict__ denom, int E) {

    __shared__ uint4 ldsW[2048];     // 32 KB: W1 bf16, pre-swizzled chunks

    const int t = threadIdx.x;
    const int lane = t & 63;
    const int lr = lane & 15;
    const int lg = lane >> 4;

    const uint4* w1v = (const uint4*)w1bf;
#pragma unroll
    for (int k = 0; k < 8; ++k) ldsW[k * 256 + t] = w1v[k * 256 + t];

    float b1v[8], w2v[8];
#pragma unroll
    for (int nf = 0; nf < 8; ++nf) { b1v[nf] = b1[nf * 16 + lr]; w2v[nf] = w2[nf * 16 + lr]; }
    const float b2v = b2p[0];

    __syncthreads();                 // only barrier in the kernel

    const int gw = blockIdx.x * WPB + (t >> 6);      // global wave id
    const long rbeg = ((long)gw * E) / NW;
    const long rend = ((long)(gw + 1) * E) / NW;     // contiguous slab [rbeg, rend)
    if (rbeg >= rend) return;
    const int nch = (int)((rend - rbeg + 15) >> 4);

    const float4* x4 = (const float4*)x;

    float v[32];                     // pooling acc: col = (i>>3)*32 + lg*8 + (i&7)
#pragma unroll
    for (int i = 0; i < 32; ++i) v[i] = 0.0f;
    float dsum = 0.0f;

    auto flush = [&](int seg) {
        // value-splitting butterfly over the 16 lr-lanes (verified R3-R7)
        {
            const bool h0 = lr & 1;
#pragma unroll
            for (int j = 0; j < 16; ++j) {
                float send = h0 ? v[j] : v[j + 16];
                float recv = __shfl_xor(send, 1, 64);
                v[j] = (h0 ? v[j + 16] : v[j]) + recv;
            }
            const bool h1 = lr & 2;
#pragma unroll
            for (int j = 0; j < 8; ++j) {
                float send = h1 ? v[j] : v[j + 8];
                float recv = __shfl_xor(send, 2, 64);
                v[j] = (h1 ? v[j + 8] : v[j]) + recv;
            }
            const bool h2 = lr & 4;
#pragma unroll
            for (int j = 0; j < 4; ++j) {
                float send = h2 ? v[j] : v[j + 4];
                float recv = __shfl_xor(send, 4, 64);
                v[j] = (h2 ? v[j + 4] : v[j]) + recv;
            }
            const bool h3 = lr & 8;
#pragma unroll
            for (int j = 0; j < 2; ++j) {
                float send = h3 ? v[j] : v[j + 2];
                float recv = __shfl_xor(send, 8, 64);
                v[j] = (h3 ? v[j + 2] : v[j]) + recv;
            }
        }
        int i0 = ((lr & 1) << 4) | ((lr & 2) << 2) | (lr & 4) | ((lr & 8) >> 2);
        int col0 = (i0 >> 3) * 32 + lg * 8 + (i0 & 7);
        atomicAdd(&num[seg * H + col0], v[0]);
        atomicAdd(&num[seg * H + col0 + 1], v[1]);
        float d = dsum;
#pragma unroll
        for (int m = 1; m <= 32; m <<= 1) d += __shfl_xor(d, m, 64);
        if (lane == 0) atomicAdd(&denom[seg], d * 0.25f);   // rows duplicated over 4 lg
#pragma unroll
        for (int i = 0; i < 32; ++i) v[i] = 0.0f;
        dsum = 0.0f;
    };

    int cur = bi[rbeg];

    for (int c = 0; c < nch; c += 2) {
        const long rA = rbeg + (long)c * 16 + lr;
        const long rB = rA + 16;
        const long rcA = rA < rend ? rA : rend - 1;  // clamp inside own slab
        const long rcB = rB < rend ? rB : rend - 1;
        const bool validA = rA < rend;
        const bool validB = rB < rend;

        // ---- load 32 rows x 128 cols (16 dwordx4/lane in flight) ----
        const float4* pA = x4 + rcA * 32 + lg * 2;
        const float4* pB = x4 + rcB * 32 + lg * 2;
        bf16x8 afA[4], afB[4];
#pragma unroll
        for (int ks = 0; ks < 4; ++ks) {
            const float4 u0 = pA[ks * 8], u1 = pA[ks * 8 + 1];
            bf16x8 a;
            a[0] = (__bf16)u0.x; a[1] = (__bf16)u0.y; a[2] = (__bf16)u0.z; a[3] = (__bf16)u0.w;
            a[4] = (__bf16)u1.x; a[5] = (__bf16)u1.y; a[6] = (__bf16)u1.z; a[7] = (__bf16)u1.w;
            afA[ks] = a;
        }
#pragma unroll
        for (int ks = 0; ks < 4; ++ks) {
            const float4 u0 = pB[ks * 8], u1 = pB[ks * 8 + 1];
            bf16x8 a;
            a[0] = (__bf16)u0.x; a[1] = (__bf16)u0.y; a[2] = (__bf16)u0.z; a[3] = (__bf16)u0.w;
            a[4] = (__bf16)u1.x; a[5] = (__bf16)u1.y; a[6] = (__bf16)u1.z; a[7] = (__bf16)u1.w;
            afB[ks] = a;
        }
        const int msA = bi[rcA];
        const int msB = bi[rcB];

        // ---- MFMA, nf-outer; one W1 B-fragment read feeds BOTH chunks ----
        float scA[4] = {0.f, 0.f, 0.f, 0.f};
        float scB[4] = {0.f, 0.f, 0.f, 0.f};
#pragma unroll
        for (int nf = 0; nf < 8; ++nf) {
            f32x4 accA = (f32x4)0.0f, accB = (f32x4)0.0f;
#pragma unroll
            for (int ks = 0; ks < 4; ++ks) {
                int j = nf * 16 + lr;
                int chunk = (j * 16 + ks * 4 + lg) ^ (j & 7);   // XOR swizzle (bank-free)
                bf16x8 bb = __builtin_bit_cast(bf16x8, ldsW[chunk]);
                accA = __builtin_amdgcn_mfma_f32_16x16x32_bf16(afA[ks], bb, accA, 0, 0, 0);
                accB = __builtin_amdgcn_mfma_f32_16x16x32_bf16(afB[ks], bb, accB, 0, 0, 0);
            }
            const float bv = b1v[nf], wv = w2v[nf];
#pragma unroll
            for (int r4 = 0; r4 < 4; ++r4) {
                scA[r4] = fmaf(fmaxf(accA[r4] + bv, 0.0f), wv, scA[r4]);
                scB[r4] = fmaf(fmaxf(accB[r4] + bv, 0.0f), wv, scB[r4]);
            }
        }
        // reduce over the 16 lr-lanes sharing each row (8 independent chains)
#pragma unroll
        for (int m = 1; m <= 8; m <<= 1)
#pragma unroll
            for (int r4 = 0; r4 < 4; ++r4) {
                scA[r4] += __shfl_xor(scA[r4], m, 64);
                scB[r4] += __shfl_xor(scB[r4], m, 64);
            }

        // e for this lane's row lr: held at lane (lg'=lr>>2, lr'=lr), entry lr&3
        const int src = ((lr >> 2) << 4) | lr;
        float s4A[4], s4B[4];
#pragma unroll
        for (int r4 = 0; r4 < 4; ++r4) {
            s4A[r4] = __shfl(scA[r4], src, 64);
            s4B[r4] = __shfl(scB[r4], src, 64);
        }
        const int rsel = lr & 3;
        const float sA = rsel == 0 ? s4A[0] : rsel == 1 ? s4A[1] : rsel == 2 ? s4A[2] : s4A[3];
        const float sB = rsel == 0 ? s4B[0] : rsel == 1 ? s4B[1] : rsel == 2 ? s4B[2] : s4B[3];
        const float eA = validA ? __expf(sA + b2v) : 0.0f;
        const float eB = validB ? __expf(sB + b2v) : 0.0f;

        // ---- accumulate chunk A, then chunk B (rows ordered) ----
        while (true) {
            const bool mine = validA && (msA == cur);
            const float em = mine ? eA : 0.0f;
#pragma unroll
            for (int ks = 0; ks < 4; ++ks)
#pragma unroll
                for (int el = 0; el < 8; ++el)
                    v[ks * 8 + el] = fmaf(em, (float)afA[ks][el], v[ks * 8 + el]);
            dsum += em;
            unsigned long long rest = __ballot(validA && msA > cur);
            if (!rest) break;
            flush(cur);
            int idx = __ffsll(rest) - 1;
            cur = __shfl(msA, idx, 64);
        }
        while (true) {
            const bool mine = validB && (msB == cur);
            const float em = mine ? eB : 0.0f;
#pragma unroll
            for (int ks = 0; ks < 4; ++ks)
#pragma unroll
                for (int el = 0; el < 8; ++el)
                    v[ks * 8 + el] = fmaf(em, (float)afB[ks][el], v[ks * 8 + el]);
            dsum += em;
            unsigned long long rest = __ballot(validB && msB > cur);
            if (!rest) break;
            flush(cur);
            int idx = __ffsll(rest) - 1;
            cur = __shfl(msB, idx, 64);
        }
    }
    flush(cur);
}

__global__ void gat_fin(const float* __restrict__ num, const float* __restrict__ denom,
                        float* __restrict__ out, int n) {
    int i = blockIdx.x * 256 + threadIdx.x;
    if (i < n) {
        float d = denom[i >> 7];
        out[i] = (d > 0.0f) ? num[i] / d : 0.0f;
    }
}

extern "C" void kernel_launch(void* const* d_in, const int* in_sizes, int n_in,
                              void* d_out, int out_size, void* d_ws, size_t ws_size,
                              hipStream_t stream) {
    const float* x  = (const float*)d_in[0];
    const int*   bi = (const int*)d_in[1];
    const float* W1 = (const float*)d_in[2];
    const float* b1 = (const float*)d_in[3];
    const float* w2 = (const float*)d_in[4];
    const float* b2 = (const float*)d_in[5];
    const int E = in_sizes[1];
    const int nseg = out_size / H;

    float* num = (float*)d_ws;                               // nseg*H f32
    float* denom = num + (size_t)nseg * H;                   // nseg f32
    unsigned short* w1bf = (unsigned short*)(denom + nseg);  // H*H bf16 (16B-aligned)

    int initN = nseg * H > H * H ? nseg * H : H * H;
    gat_init<<<(initN + 255) / 256, 256, 0, stream>>>(W1, num, denom, w1bf, nseg);
    gat_main<<<NBLK, 256, 0, stream>>>(x, bi, w1bf, b1, w2, b2, num, denom, E);
    gat_fin<<<(out_size + 255) / 256, 256, 0, stream>>>(num, denom, (float*)d_out, out_size);
}